// Round 6
// baseline (815.097 us; speedup 1.0000x reference)
//
// Round 6: T4 counted-vmcnt pipeline (m218 recipe) — raw s_barrier + explicit
// s_waitcnt vmcnt(8), depth-2 prefetch, nb[] moved to LDS so no stray global
// loads perturb the vmcnt bookkeeping. Math/layouts unchanged (absmax==0 path).
#include <hip/hip_runtime.h>
#include <cstdint>
#include <cstddef>

#define K_DIM 512
#define BM 128
#define BN 128
#define BK 32
#define JCHUNKS 8
#define PER_MAX 8

typedef __attribute__((ext_vector_type(8))) __bf16 bf16x8;
typedef __attribute__((ext_vector_type(8))) short short8;
typedef __attribute__((ext_vector_type(4))) float f32x4;

__device__ __forceinline__ ushort bf16_rn(float x) {
    uint u = __float_as_uint(x);
    return (ushort)((u + 0x7fffu + ((u >> 16) & 1u)) >> 16);
}

// ---------------------------------------------------------------------------
// Kernel 0: row norms of A and B (padded), init vmin[] = +inf, pad nb = +inf.
// ---------------------------------------------------------------------------
__global__ __launch_bounds__(256) void norms_init_kernel(
    const float* __restrict__ A, const float* __restrict__ B,
    float* __restrict__ na, float* __restrict__ nb,
    unsigned* __restrict__ vmin, int N, int M, int Npad, int Mpad)
{
    int w = (int)((blockIdx.x * blockDim.x + threadIdx.x) >> 6);
    int lane = threadIdx.x & 63;
    if (w >= Npad + Mpad) return;
    if (w < Npad) {
        float s = 0.f;
        if (w < N) {
            const float* src = A + (size_t)w * K_DIM + lane * 8;
            float4 v0 = *(const float4*)src;
            float4 v1 = *(const float4*)(src + 4);
            s = v0.x*v0.x + v0.y*v0.y + v0.z*v0.z + v0.w*v0.w
              + v1.x*v1.x + v1.y*v1.y + v1.z*v1.z + v1.w*v1.w;
            #pragma unroll
            for (int m = 1; m < 64; m <<= 1) s += __shfl_xor(s, m, 64);
        }
        if (lane == 0) { na[w] = s; vmin[w] = 0x7f800000u; }
    } else {
        int j = w - Npad;
        float s = __builtin_inff();   // padded centers never win the min
        if (j < M) {
            const float* src = B + (size_t)j * K_DIM + lane * 8;
            float4 v0 = *(const float4*)src;
            float4 v1 = *(const float4*)(src + 4);
            s = v0.x*v0.x + v0.y*v0.y + v0.z*v0.z + v0.w*v0.w
              + v1.x*v1.x + v1.y*v1.y + v1.z*v1.z + v1.w*v1.w;
            #pragma unroll
            for (int m = 1; m < 64; m <<= 1) s += __shfl_xor(s, m, 64);
        }
        if (lane == 0) nb[j] = s;
    }
}

// ---------------------------------------------------------------------------
// Kernel 1: preconvert fp32 -> bf16 hi/lo in the per-(tile,kt) LDS image
// layout [tile][kt][g][m][8] so the GEMM can global_load_lds it linearly.
// ---------------------------------------------------------------------------
__global__ __launch_bounds__(256) void preconvert_kernel(
    const float* __restrict__ src, ushort* __restrict__ hiW, ushort* __restrict__ loW,
    int realRows, int padRows)
{
    int c = blockIdx.x * 256 + threadIdx.x;            // chunk id
    int total = padRows * (K_DIM / 8);
    if (c >= total) return;
    int m    = c & (BM - 1);
    int g    = (c >> 7) & 3;
    int kt   = (c >> 9) & 15;
    int tile = c >> 13;
    int row  = tile * BM + m;
    int k    = kt * BK + g * 8;
    float f[8];
    if (row < realRows) {
        float4 x0 = *(const float4*)(src + (size_t)row * K_DIM + k);
        float4 x1 = *(const float4*)(src + (size_t)row * K_DIM + k + 4);
        f[0]=x0.x; f[1]=x0.y; f[2]=x0.z; f[3]=x0.w;
        f[4]=x1.x; f[5]=x1.y; f[6]=x1.z; f[7]=x1.w;
    } else {
        #pragma unroll
        for (int q = 0; q < 8; ++q) f[q] = 0.f;
    }
    short8 hv, lv;
    #pragma unroll
    for (int q = 0; q < 8; ++q) {
        ushort hb = bf16_rn(f[q]);
        float  lo = f[q] - __uint_as_float((uint)hb << 16);
        hv[q] = (short)hb;
        lv[q] = (short)bf16_rn(lo);
    }
    *(short8*)(hiW + (size_t)c * 8) = hv;
    *(short8*)(loW + (size_t)c * 8) = lv;
}

// ---------------------------------------------------------------------------
// Kernel 2: MFMA GEMM + fused row-min. Depth-2 counted-vmcnt pipeline:
// STAGE(t) and STAGE(t+1) in flight; per iter: wait vmcnt(8) (t's loads),
// barrier, compute buf[t&1], barrier, STAGE(t+2) into freed buffer.
// ---------------------------------------------------------------------------
__global__ __launch_bounds__(256, 2) void gemm_min_pre(
    const ushort* __restrict__ AhiW, const ushort* __restrict__ AloW,
    const ushort* __restrict__ BhiW, const ushort* __restrict__ BloW,
    const float* __restrict__ na, const float* __restrict__ nb,
    unsigned* __restrict__ vmin, int N, int njt)
{
    __shared__ ushort Ah[2][4096], Al[2][4096], Bh[2][4096], Bl[2][4096]; // 64 KB
    __shared__ float  nbs[PER_MAX * BN];                                  // 4 KB

    const int tid  = threadIdx.x;
    const int lane = tid & 63;
    const int wave = tid >> 6;
    const int wr = (wave >> 1) * 64;
    const int wc = (wave & 1) * 64;
    const int tr = lane & 15;
    const int tg = lane >> 4;
    const int tile = blockIdx.x;

    const int per = (njt + JCHUNKS - 1) / JCHUNKS;
    const int jt_begin = min((int)blockIdx.y * per, njt);
    const int jt_end   = min(jt_begin + per, njt);
    const int njt_loc  = jt_end - jt_begin;

    float localmin[16];
    #pragma unroll
    for (int u = 0; u < 16; ++u) localmin[u] = __builtin_inff();

    auto STAGE = [&](int buf, int t) {
        const int jt = jt_begin + (t >> 4);
        const int kt = t & 15;
        const ushort* sAh = AhiW + ((size_t)tile * 16 + kt) * 4096;
        const ushort* sAl = AloW + ((size_t)tile * 16 + kt) * 4096;
        const ushort* sBh = BhiW + ((size_t)jt   * 16 + kt) * 4096;
        const ushort* sBl = BloW + ((size_t)jt   * 16 + kt) * 4096;
        #pragma unroll
        for (int q = 0; q < 2; ++q) {
            int gi = (q * 256 + tid) * 8;          // per-lane global offset
            int li = (q * 256 + wave * 64) * 8;    // wave-uniform LDS base
            __builtin_amdgcn_global_load_lds(
                (const __attribute__((address_space(1))) void*)(sAh + gi),
                (__attribute__((address_space(3))) void*)(&Ah[buf][li]), 16, 0, 0);
            __builtin_amdgcn_global_load_lds(
                (const __attribute__((address_space(1))) void*)(sAl + gi),
                (__attribute__((address_space(3))) void*)(&Al[buf][li]), 16, 0, 0);
            __builtin_amdgcn_global_load_lds(
                (const __attribute__((address_space(1))) void*)(sBh + gi),
                (__attribute__((address_space(3))) void*)(&Bh[buf][li]), 16, 0, 0);
            __builtin_amdgcn_global_load_lds(
                (const __attribute__((address_space(1))) void*)(sBl + gi),
                (__attribute__((address_space(3))) void*)(&Bl[buf][li]), 16, 0, 0);
        }
    };

    if (njt_loc > 0) {
        const int T = njt_loc * 16;

        // prologue: nb chunk -> LDS (so the K-loop has NO global loads that
        // would perturb the manual vmcnt bookkeeping)
        for (int x = tid; x < njt_loc * BN; x += 256)
            nbs[x] = nb[jt_begin * BN + x];

        STAGE(0, 0);
        if (T > 1) STAGE(1, 1);

        asm volatile("s_waitcnt lgkmcnt(0)" ::: "memory"); // nbs ds_writes done
        __builtin_amdgcn_sched_barrier(0);
        __builtin_amdgcn_s_barrier();                       // nbs visible

        f32x4 acc[4][4];
        #pragma unroll
        for (int fi = 0; fi < 4; ++fi)
            #pragma unroll
            for (int fj = 0; fj < 4; ++fj) acc[fi][fj] = (f32x4)0.f;

        int cur = 0;
        for (int t = 0; t < T; ++t) {
            // wait for buf[cur]'s 8 loads (leave t+1's 8 in flight)
            if (t + 1 < T) asm volatile("s_waitcnt vmcnt(8)" ::: "memory");
            else           asm volatile("s_waitcnt vmcnt(0)" ::: "memory");
            __builtin_amdgcn_sched_barrier(0);
            __builtin_amdgcn_s_barrier();      // all waves' buf[cur] data landed
            __builtin_amdgcn_sched_barrier(0);

            bf16x8 a_h[4], a_l[4], b_h[4], b_l[4];
            #pragma unroll
            for (int fi = 0; fi < 4; ++fi) {
                int ra = (tg * 128 + wr + fi * 16 + tr) * 8;
                a_h[fi] = *(const bf16x8*)(&Ah[cur][ra]);
                a_l[fi] = *(const bf16x8*)(&Al[cur][ra]);
            }
            #pragma unroll
            for (int fj = 0; fj < 4; ++fj) {
                int rb = (tg * 128 + wc + fj * 16 + tr) * 8;
                b_h[fj] = *(const bf16x8*)(&Bh[cur][rb]);
                b_l[fj] = *(const bf16x8*)(&Bl[cur][rb]);
            }
            #pragma unroll
            for (int fi = 0; fi < 4; ++fi)
                #pragma unroll
                for (int fj = 0; fj < 4; ++fj) {
                    acc[fi][fj] = __builtin_amdgcn_mfma_f32_16x16x32_bf16(a_h[fi], b_h[fj], acc[fi][fj], 0, 0, 0);
                    acc[fi][fj] = __builtin_amdgcn_mfma_f32_16x16x32_bf16(a_h[fi], b_l[fj], acc[fi][fj], 0, 0, 0);
                    acc[fi][fj] = __builtin_amdgcn_mfma_f32_16x16x32_bf16(a_l[fi], b_h[fj], acc[fi][fj], 0, 0, 0);
                }

            if ((t & 15) == 15) {              // end of a jt: fold into row-min
                const int jl = t >> 4;         // local jt index
                #pragma unroll
                for (int fj = 0; fj < 4; ++fj) {
                    float nbv = nbs[jl * BN + wc + fj * 16 + tr];
                    #pragma unroll
                    for (int fi = 0; fi < 4; ++fi)
                        #pragma unroll
                        for (int r = 0; r < 4; ++r) {
                            float s = fmaf(-2.f, acc[fi][fj][r], nbv);
                            localmin[fi * 4 + r] = fminf(localmin[fi * 4 + r], s);
                        }
                }
                #pragma unroll
                for (int fi = 0; fi < 4; ++fi)
                    #pragma unroll
                    for (int fj = 0; fj < 4; ++fj) acc[fi][fj] = (f32x4)0.f;
            }

            __builtin_amdgcn_sched_barrier(0); // pin ds_reads before barrier
            __builtin_amdgcn_s_barrier();      // all waves done with buf[cur]
            if (t + 2 < T) STAGE(cur, t + 2);  // overwrite freed buffer
            cur ^= 1;
        }
    }

    // reduce localmin across the 16 tr lanes of each row group (same wave)
    #pragma unroll
    for (int u = 0; u < 16; ++u) {
        float v = localmin[u];
        #pragma unroll
        for (int m = 1; m < 16; m <<= 1) v = fminf(v, __shfl_xor(v, m, 64));
        localmin[u] = v;
    }
    if (tr == 0) {
        #pragma unroll
        for (int fi = 0; fi < 4; ++fi)
            #pragma unroll
            for (int r = 0; r < 4; ++r) {
                int i = tile * BM + wr + fi * 16 + tg * 4 + r;
                if (i < N) {
                    float v = fmaxf(na[i] + localmin[fi * 4 + r], 0.f);
                    atomicMin(&vmin[i], __float_as_uint(v));
                }
            }
    }
}

// ---------------------------------------------------------------------------
// Kernel 2b: fallback — converts fp32->bf16 hi/lo in staging (only if ws too
// small for preconversion or per > PER_MAX). Correctness path only.
// ---------------------------------------------------------------------------
__global__ __launch_bounds__(256, 2) void gemm_min_fused(
    const float* __restrict__ A, const float* __restrict__ B,
    const float* __restrict__ na, const float* __restrict__ nb,
    unsigned* __restrict__ vmin, int N, int M, int njt)
{
    __shared__ ushort Ah[4096], Al[4096], Bh[4096], Bl[4096];

    const int tid  = threadIdx.x;
    const int lane = tid & 63;
    const int wave = tid >> 6;
    const int wr = (wave >> 1) * 64;
    const int wc = (wave & 1) * 64;
    const int tr = lane & 15;
    const int tg = lane >> 4;
    const int i0 = blockIdx.x * BM;

    const int sm = tid & 127;
    const int sh = tid >> 7;

    const int per = (njt + JCHUNKS - 1) / JCHUNKS;
    const int jt_begin = min((int)blockIdx.y * per, njt);
    const int jt_end   = min(jt_begin + per, njt);

    float localmin[16];
    #pragma unroll
    for (int u = 0; u < 16; ++u) localmin[u] = __builtin_inff();

    for (int jt = jt_begin; jt < jt_end; ++jt) {
        const int j0 = jt * BN;
        f32x4 acc[4][4];
        #pragma unroll
        for (int fi = 0; fi < 4; ++fi)
            #pragma unroll
            for (int fj = 0; fj < 4; ++fj) acc[fi][fj] = (f32x4)0.f;

        for (int kt = 0; kt < K_DIM / BK; ++kt) {
            const int k0 = kt * BK + sh * 16;
            {
                float f[16];
                int gi = i0 + sm;
                if (gi < N) {
                    const float* p = A + (size_t)gi * K_DIM + k0;
                    #pragma unroll
                    for (int q = 0; q < 4; ++q) {
                        float4 x = *(const float4*)(p + q * 4);
                        f[q*4+0]=x.x; f[q*4+1]=x.y; f[q*4+2]=x.z; f[q*4+3]=x.w;
                    }
                } else {
                    #pragma unroll
                    for (int q = 0; q < 16; ++q) f[q] = 0.f;
                }
                short8 h0, h1, l0, l1;
                #pragma unroll
                for (int q = 0; q < 8; ++q) {
                    uint u = __float_as_uint(f[q]);
                    h0[q] = (short)(u >> 16);
                    float lo = f[q] - __uint_as_float(u & 0xffff0000u);
                    l0[q] = (short)(__float_as_uint(lo) >> 16);
                }
                #pragma unroll
                for (int q = 0; q < 8; ++q) {
                    uint u = __float_as_uint(f[8+q]);
                    h1[q] = (short)(u >> 16);
                    float lo = f[8+q] - __uint_as_float(u & 0xffff0000u);
                    l1[q] = (short)(__float_as_uint(lo) >> 16);
                }
                int g0 = sh * 2;
                *(short8*)(Ah + (g0 * 128 + sm) * 8)       = h0;
                *(short8*)(Ah + ((g0 + 1) * 128 + sm) * 8) = h1;
                *(short8*)(Al + (g0 * 128 + sm) * 8)       = l0;
                *(short8*)(Al + ((g0 + 1) * 128 + sm) * 8) = l1;
            }
            {
                float f[16];
                int gj = j0 + sm;
                if (gj < M) {
                    const float* p = B + (size_t)gj * K_DIM + k0;
                    #pragma unroll
                    for (int q = 0; q < 4; ++q) {
                        float4 x = *(const float4*)(p + q * 4);
                        f[q*4+0]=x.x; f[q*4+1]=x.y; f[q*4+2]=x.z; f[q*4+3]=x.w;
                    }
                } else {
                    #pragma unroll
                    for (int q = 0; q < 16; ++q) f[q] = 0.f;
                }
                short8 h0, h1, l0, l1;
                #pragma unroll
                for (int q = 0; q < 8; ++q) {
                    uint u = __float_as_uint(f[q]);
                    h0[q] = (short)(u >> 16);
                    float lo = f[q] - __uint_as_float(u & 0xffff0000u);
                    l0[q] = (short)(__float_as_uint(lo) >> 16);
                }
                #pragma unroll
                for (int q = 0; q < 8; ++q) {
                    uint u = __float_as_uint(f[8+q]);
                    h1[q] = (short)(u >> 16);
                    float lo = f[8+q] - __uint_as_float(u & 0xffff0000u);
                    l1[q] = (short)(__float_as_uint(lo) >> 16);
                }
                int g0 = sh * 2;
                *(short8*)(Bh + (g0 * 128 + sm) * 8)       = h0;
                *(short8*)(Bh + ((g0 + 1) * 128 + sm) * 8) = h1;
                *(short8*)(Bl + (g0 * 128 + sm) * 8)       = l0;
                *(short8*)(Bl + ((g0 + 1) * 128 + sm) * 8) = l1;
            }
            __syncthreads();

            bf16x8 a_h[4], a_l[4], b_h[4], b_l[4];
            #pragma unroll
            for (int fi = 0; fi < 4; ++fi) {
                int ra = (tg * 128 + wr + fi * 16 + tr) * 8;
                a_h[fi] = *(const bf16x8*)(Ah + ra);
                a_l[fi] = *(const bf16x8*)(Al + ra);
            }
            #pragma unroll
            for (int fj = 0; fj < 4; ++fj) {
                int rb = (tg * 128 + wc + fj * 16 + tr) * 8;
                b_h[fj] = *(const bf16x8*)(Bh + rb);
                b_l[fj] = *(const bf16x8*)(Bl + rb);
            }
            #pragma unroll
            for (int fi = 0; fi < 4; ++fi)
                #pragma unroll
                for (int fj = 0; fj < 4; ++fj) {
                    acc[fi][fj] = __builtin_amdgcn_mfma_f32_16x16x32_bf16(a_h[fi], b_h[fj], acc[fi][fj], 0, 0, 0);
                    acc[fi][fj] = __builtin_amdgcn_mfma_f32_16x16x32_bf16(a_h[fi], b_l[fj], acc[fi][fj], 0, 0, 0);
                    acc[fi][fj] = __builtin_amdgcn_mfma_f32_16x16x32_bf16(a_l[fi], b_h[fj], acc[fi][fj], 0, 0, 0);
                }
            __syncthreads();
        }

        #pragma unroll
        for (int fj = 0; fj < 4; ++fj) {
            int j = j0 + wc + fj * 16 + tr;
            float nbv = nb[j];
            #pragma unroll
            for (int fi = 0; fi < 4; ++fi)
                #pragma unroll
                for (int r = 0; r < 4; ++r) {
                    float s = fmaf(-2.f, acc[fi][fj][r], nbv);
                    localmin[fi * 4 + r] = fminf(localmin[fi * 4 + r], s);
                }
        }
    }

    #pragma unroll
    for (int u = 0; u < 16; ++u) {
        float v = localmin[u];
        #pragma unroll
        for (int m = 1; m < 16; m <<= 1) v = fminf(v, __shfl_xor(v, m, 64));
        localmin[u] = v;
    }
    if (tr == 0) {
        #pragma unroll
        for (int fi = 0; fi < 4; ++fi)
            #pragma unroll
            for (int r = 0; r < 4; ++r) {
                int i = i0 + wr + fi * 16 + tg * 4 + r;
                if (i < N) {
                    float v = fmaxf(na[i] + localmin[fi * 4 + r], 0.f);
                    atomicMin(&vmin[i], __float_as_uint(v));
                }
            }
    }
}

// ---------------------------------------------------------------------------
// Kernel 3: argmax over vmin (uint bits of non-negative floats).
// ---------------------------------------------------------------------------
__global__ __launch_bounds__(1024) void argmax_kernel(
    const unsigned* __restrict__ vmin, float* __restrict__ out, int N)
{
    unsigned long long best = 0ull;
    for (int i = threadIdx.x; i < N; i += 1024) {
        unsigned long long p =
            ((unsigned long long)vmin[i] << 32) | (unsigned)(~i);
        if (p > best) best = p;
    }
    #pragma unroll
    for (int m = 1; m < 64; m <<= 1) {
        unsigned hi = (unsigned)(best >> 32), lo = (unsigned)best;
        unsigned ohi = __shfl_xor(hi, m, 64);
        unsigned olo = __shfl_xor(lo, m, 64);
        unsigned long long o = ((unsigned long long)ohi << 32) | olo;
        if (o > best) best = o;
    }
    __shared__ unsigned long long sb[16];
    int lane = threadIdx.x & 63, w = threadIdx.x >> 6;
    if (lane == 0) sb[w] = best;
    __syncthreads();
    if (threadIdx.x == 0) {
        unsigned long long b = sb[0];
        #pragma unroll
        for (int w2 = 1; w2 < 16; ++w2) if (sb[w2] > b) b = sb[w2];
        unsigned idx = ~(unsigned)(b & 0xFFFFFFFFull);
        float v = __uint_as_float((unsigned)(b >> 32));
        out[0] = (float)idx;
        out[1] = sqrtf(v);
    }
}

// ---------------------------------------------------------------------------
extern "C" void kernel_launch(void* const* d_in, const int* in_sizes, int n_in,
                              void* d_out, int out_size, void* d_ws, size_t ws_size,
                              hipStream_t stream)
{
    const float* A = (const float*)d_in[0];
    const float* B = (const float*)d_in[1];
    const int N = in_sizes[0] / K_DIM;           // 50000
    const int M = in_sizes[1] / K_DIM;           // 5000
    const int ntile = (N + BM - 1) / BM;         // 391
    const int njt   = (M + BN - 1) / BN;         // 40
    const int Npad = ntile * BM, Mpad = njt * BN;
    const int per  = (njt + JCHUNKS - 1) / JCHUNKS;  // 5

    char* ws = (char*)d_ws;
    float*    na   = (float*)ws;                     // Npad
    float*    nb   = na + Npad;                      // Mpad
    unsigned* vmin = (unsigned*)(nb + Mpad);         // Npad
    size_t off = ((size_t)(Npad + Mpad + Npad) * 4 + 255) & ~(size_t)255;
    size_t sizeA = (size_t)Npad * K_DIM;             // ushorts
    size_t sizeB = (size_t)Mpad * K_DIM;
    ushort* AhiW = (ushort*)(ws + off);
    ushort* AloW = AhiW + sizeA;
    ushort* BhiW = AloW + sizeA;
    ushort* BloW = BhiW + sizeB;
    size_t need = off + 2 * (sizeA + sizeB) * sizeof(ushort);

    float* out = (float*)d_out;

    int waves = Npad + Mpad;
    hipLaunchKernelGGL(norms_init_kernel, dim3((waves + 3) / 4), dim3(256), 0, stream,
                       A, B, na, nb, vmin, N, M, Npad, Mpad);

    if (ws_size >= need && per <= PER_MAX) {
        hipLaunchKernelGGL(preconvert_kernel, dim3((Npad * 64 + 255) / 256), dim3(256), 0, stream,
                           A, AhiW, AloW, N, Npad);
        hipLaunchKernelGGL(preconvert_kernel, dim3((Mpad * 64 + 255) / 256), dim3(256), 0, stream,
                           B, BhiW, BloW, M, Mpad);
        hipLaunchKernelGGL(gemm_min_pre, dim3(ntile, JCHUNKS), dim3(256), 0, stream,
                           AhiW, AloW, BhiW, BloW, na, nb, vmin, N, njt);
    } else {
        hipLaunchKernelGGL(gemm_min_fused, dim3(ntile, JCHUNKS), dim3(256), 0, stream,
                           A, B, na, nb, vmin, N, M, njt);
    }

    hipLaunchKernelGGL(argmax_kernel, dim3(1), dim3(1024), 0, stream,
                       vmin, out, N);
}

// Round 7
// 745.826 us; speedup vs baseline: 1.0929x; 1.0929x over previous
//
// Round 7: revert round-6 pins (m141-style regression confirmed: sched_barrier(0)
// + double s_barrier cost more than the vmcnt drain saved). Round-5 pipeline
// restored; NEW: grid swapped to (chunk, tile) so the 8 blocks sharing an
// A-tile are dispatch-adjacent -> A served from L3 instead of HBM re-fetch.
#include <hip/hip_runtime.h>
#include <cstdint>
#include <cstddef>

#define K_DIM 512
#define BM 128
#define BN 128
#define BK 32
#define JCHUNKS 8

typedef __attribute__((ext_vector_type(8))) __bf16 bf16x8;
typedef __attribute__((ext_vector_type(8))) short short8;
typedef __attribute__((ext_vector_type(4))) float f32x4;

__device__ __forceinline__ ushort bf16_rn(float x) {
    uint u = __float_as_uint(x);
    return (ushort)((u + 0x7fffu + ((u >> 16) & 1u)) >> 16);
}

// ---------------------------------------------------------------------------
// Kernel 0: row norms of A and B (padded), init vmin[] = +inf, pad nb = +inf.
// ---------------------------------------------------------------------------
__global__ __launch_bounds__(256) void norms_init_kernel(
    const float* __restrict__ A, const float* __restrict__ B,
    float* __restrict__ na, float* __restrict__ nb,
    unsigned* __restrict__ vmin, int N, int M, int Npad, int Mpad)
{
    int w = (int)((blockIdx.x * blockDim.x + threadIdx.x) >> 6);
    int lane = threadIdx.x & 63;
    if (w >= Npad + Mpad) return;
    if (w < Npad) {
        float s = 0.f;
        if (w < N) {
            const float* src = A + (size_t)w * K_DIM + lane * 8;
            float4 v0 = *(const float4*)src;
            float4 v1 = *(const float4*)(src + 4);
            s = v0.x*v0.x + v0.y*v0.y + v0.z*v0.z + v0.w*v0.w
              + v1.x*v1.x + v1.y*v1.y + v1.z*v1.z + v1.w*v1.w;
            #pragma unroll
            for (int m = 1; m < 64; m <<= 1) s += __shfl_xor(s, m, 64);
        }
        if (lane == 0) { na[w] = s; vmin[w] = 0x7f800000u; }
    } else {
        int j = w - Npad;
        float s = __builtin_inff();   // padded centers never win the min
        if (j < M) {
            const float* src = B + (size_t)j * K_DIM + lane * 8;
            float4 v0 = *(const float4*)src;
            float4 v1 = *(const float4*)(src + 4);
            s = v0.x*v0.x + v0.y*v0.y + v0.z*v0.z + v0.w*v0.w
              + v1.x*v1.x + v1.y*v1.y + v1.z*v1.z + v1.w*v1.w;
            #pragma unroll
            for (int m = 1; m < 64; m <<= 1) s += __shfl_xor(s, m, 64);
        }
        if (lane == 0) nb[j] = s;
    }
}

// ---------------------------------------------------------------------------
// Kernel 1: preconvert fp32 -> bf16 hi/lo in the per-(tile,kt) LDS image
// layout [tile][kt][g][m][8] so the GEMM can global_load_lds it linearly.
// ---------------------------------------------------------------------------
__global__ __launch_bounds__(256) void preconvert_kernel(
    const float* __restrict__ src, ushort* __restrict__ hiW, ushort* __restrict__ loW,
    int realRows, int padRows)
{
    int c = blockIdx.x * 256 + threadIdx.x;            // chunk id
    int total = padRows * (K_DIM / 8);
    if (c >= total) return;
    int m    = c & (BM - 1);
    int g    = (c >> 7) & 3;
    int kt   = (c >> 9) & 15;
    int tile = c >> 13;
    int row  = tile * BM + m;
    int k    = kt * BK + g * 8;
    float f[8];
    if (row < realRows) {
        float4 x0 = *(const float4*)(src + (size_t)row * K_DIM + k);
        float4 x1 = *(const float4*)(src + (size_t)row * K_DIM + k + 4);
        f[0]=x0.x; f[1]=x0.y; f[2]=x0.z; f[3]=x0.w;
        f[4]=x1.x; f[5]=x1.y; f[6]=x1.z; f[7]=x1.w;
    } else {
        #pragma unroll
        for (int q = 0; q < 8; ++q) f[q] = 0.f;
    }
    short8 hv, lv;
    #pragma unroll
    for (int q = 0; q < 8; ++q) {
        ushort hb = bf16_rn(f[q]);
        float  lo = f[q] - __uint_as_float((uint)hb << 16);
        hv[q] = (short)hb;
        lv[q] = (short)bf16_rn(lo);
    }
    *(short8*)(hiW + (size_t)c * 8) = hv;
    *(short8*)(loW + (size_t)c * 8) = lv;
}

// ---------------------------------------------------------------------------
// Kernel 2: MFMA GEMM + fused row-min, double-buffered 2-phase pipeline
// (round-5 structure). blockIdx.x = j-chunk, blockIdx.y = A-tile so the
// JCHUNKS blocks sharing one A-tile are dispatch-adjacent (L3 reuse).
// ---------------------------------------------------------------------------
__global__ __launch_bounds__(256, 2) void gemm_min_pre(
    const ushort* __restrict__ AhiW, const ushort* __restrict__ AloW,
    const ushort* __restrict__ BhiW, const ushort* __restrict__ BloW,
    const float* __restrict__ na, const float* __restrict__ nb,
    unsigned* __restrict__ vmin, int N, int njt)
{
    __shared__ ushort Ah[2][4096], Al[2][4096], Bh[2][4096], Bl[2][4096]; // 64 KB

    const int tid  = threadIdx.x;
    const int lane = tid & 63;
    const int wave = tid >> 6;
    const int wr = (wave >> 1) * 64;
    const int wc = (wave & 1) * 64;
    const int tr = lane & 15;
    const int tg = lane >> 4;
    const int tile = blockIdx.y;          // A-tile (dispatch-slow axis)

    const int per = (njt + JCHUNKS - 1) / JCHUNKS;
    const int jt_begin = min((int)blockIdx.x * per, njt);   // chunk = fast axis
    const int jt_end   = min(jt_begin + per, njt);

    float localmin[16];
    #pragma unroll
    for (int u = 0; u < 16; ++u) localmin[u] = __builtin_inff();

    auto STAGE = [&](int buf, int t) {
        const int jt = jt_begin + (t >> 4);
        const int kt = t & 15;
        const ushort* sAh = AhiW + ((size_t)tile * 16 + kt) * 4096;
        const ushort* sAl = AloW + ((size_t)tile * 16 + kt) * 4096;
        const ushort* sBh = BhiW + ((size_t)jt   * 16 + kt) * 4096;
        const ushort* sBl = BloW + ((size_t)jt   * 16 + kt) * 4096;
        #pragma unroll
        for (int q = 0; q < 2; ++q) {
            int gi = (q * 256 + tid) * 8;          // per-lane global offset
            int li = (q * 256 + wave * 64) * 8;    // wave-uniform LDS base
            __builtin_amdgcn_global_load_lds(
                (const __attribute__((address_space(1))) void*)(sAh + gi),
                (__attribute__((address_space(3))) void*)(&Ah[buf][li]), 16, 0, 0);
            __builtin_amdgcn_global_load_lds(
                (const __attribute__((address_space(1))) void*)(sAl + gi),
                (__attribute__((address_space(3))) void*)(&Al[buf][li]), 16, 0, 0);
            __builtin_amdgcn_global_load_lds(
                (const __attribute__((address_space(1))) void*)(sBh + gi),
                (__attribute__((address_space(3))) void*)(&Bh[buf][li]), 16, 0, 0);
            __builtin_amdgcn_global_load_lds(
                (const __attribute__((address_space(1))) void*)(sBl + gi),
                (__attribute__((address_space(3))) void*)(&Bl[buf][li]), 16, 0, 0);
        }
    };

    if (jt_begin < jt_end) {
        const int T = (jt_end - jt_begin) * 16;

        STAGE(0, 0);
        __syncthreads();           // drain prologue loads
        int cur = 0;

        f32x4 acc[4][4];
        #pragma unroll
        for (int fi = 0; fi < 4; ++fi)
            #pragma unroll
            for (int fj = 0; fj < 4; ++fj) acc[fi][fj] = (f32x4)0.f;

        for (int t = 0; t < T; ++t) {
            if (t + 1 < T) STAGE(cur ^ 1, t + 1);   // issue-early prefetch

            bf16x8 a_h[4], a_l[4], b_h[4], b_l[4];
            #pragma unroll
            for (int fi = 0; fi < 4; ++fi) {
                int ra = (tg * 128 + wr + fi * 16 + tr) * 8;
                a_h[fi] = *(const bf16x8*)(&Ah[cur][ra]);
                a_l[fi] = *(const bf16x8*)(&Al[cur][ra]);
            }
            #pragma unroll
            for (int fj = 0; fj < 4; ++fj) {
                int rb = (tg * 128 + wc + fj * 16 + tr) * 8;
                b_h[fj] = *(const bf16x8*)(&Bh[cur][rb]);
                b_l[fj] = *(const bf16x8*)(&Bl[cur][rb]);
            }
            #pragma unroll
            for (int fi = 0; fi < 4; ++fi)
                #pragma unroll
                for (int fj = 0; fj < 4; ++fj) {
                    acc[fi][fj] = __builtin_amdgcn_mfma_f32_16x16x32_bf16(a_h[fi], b_h[fj], acc[fi][fj], 0, 0, 0);
                    acc[fi][fj] = __builtin_amdgcn_mfma_f32_16x16x32_bf16(a_h[fi], b_l[fj], acc[fi][fj], 0, 0, 0);
                    acc[fi][fj] = __builtin_amdgcn_mfma_f32_16x16x32_bf16(a_l[fi], b_h[fj], acc[fi][fj], 0, 0, 0);
                }

            if ((t & 15) == 15) {
                const int jt = jt_begin + (t >> 4);
                #pragma unroll
                for (int fj = 0; fj < 4; ++fj) {
                    int j = jt * BN + wc + fj * 16 + tr;
                    float nbv = nb[j];                 // padded with +inf
                    #pragma unroll
                    for (int fi = 0; fi < 4; ++fi)
                        #pragma unroll
                        for (int r = 0; r < 4; ++r) {
                            float s = fmaf(-2.f, acc[fi][fj][r], nbv);
                            localmin[fi * 4 + r] = fminf(localmin[fi * 4 + r], s);
                        }
                }
                #pragma unroll
                for (int fi = 0; fi < 4; ++fi)
                    #pragma unroll
                    for (int fj = 0; fj < 4; ++fj) acc[fi][fj] = (f32x4)0.f;
            }

            __syncthreads();       // barrier: drains prefetch vmcnt + lgkm
            cur ^= 1;
        }
    }

    // reduce localmin across the 16 tr lanes of each row group (same wave)
    #pragma unroll
    for (int u = 0; u < 16; ++u) {
        float v = localmin[u];
        #pragma unroll
        for (int m = 1; m < 16; m <<= 1) v = fminf(v, __shfl_xor(v, m, 64));
        localmin[u] = v;
    }
    if (tr == 0) {
        #pragma unroll
        for (int fi = 0; fi < 4; ++fi)
            #pragma unroll
            for (int r = 0; r < 4; ++r) {
                int i = tile * BM + wr + fi * 16 + tg * 4 + r;
                if (i < N) {
                    float v = fmaxf(na[i] + localmin[fi * 4 + r], 0.f);
                    atomicMin(&vmin[i], __float_as_uint(v));
                }
            }
    }
}

// ---------------------------------------------------------------------------
// Kernel 2b: fallback — converts fp32->bf16 hi/lo in staging (only if ws too
// small for preconversion). Correctness path only.
// ---------------------------------------------------------------------------
__global__ __launch_bounds__(256, 2) void gemm_min_fused(
    const float* __restrict__ A, const float* __restrict__ B,
    const float* __restrict__ na, const float* __restrict__ nb,
    unsigned* __restrict__ vmin, int N, int M, int njt)
{
    __shared__ ushort Ah[4096], Al[4096], Bh[4096], Bl[4096];

    const int tid  = threadIdx.x;
    const int lane = tid & 63;
    const int wave = tid >> 6;
    const int wr = (wave >> 1) * 64;
    const int wc = (wave & 1) * 64;
    const int tr = lane & 15;
    const int tg = lane >> 4;
    const int i0 = blockIdx.y * BM;

    const int sm = tid & 127;
    const int sh = tid >> 7;

    const int per = (njt + JCHUNKS - 1) / JCHUNKS;
    const int jt_begin = min((int)blockIdx.x * per, njt);
    const int jt_end   = min(jt_begin + per, njt);

    float localmin[16];
    #pragma unroll
    for (int u = 0; u < 16; ++u) localmin[u] = __builtin_inff();

    for (int jt = jt_begin; jt < jt_end; ++jt) {
        const int j0 = jt * BN;
        f32x4 acc[4][4];
        #pragma unroll
        for (int fi = 0; fi < 4; ++fi)
            #pragma unroll
            for (int fj = 0; fj < 4; ++fj) acc[fi][fj] = (f32x4)0.f;

        for (int kt = 0; kt < K_DIM / BK; ++kt) {
            const int k0 = kt * BK + sh * 16;
            {
                float f[16];
                int gi = i0 + sm;
                if (gi < N) {
                    const float* p = A + (size_t)gi * K_DIM + k0;
                    #pragma unroll
                    for (int q = 0; q < 4; ++q) {
                        float4 x = *(const float4*)(p + q * 4);
                        f[q*4+0]=x.x; f[q*4+1]=x.y; f[q*4+2]=x.z; f[q*4+3]=x.w;
                    }
                } else {
                    #pragma unroll
                    for (int q = 0; q < 16; ++q) f[q] = 0.f;
                }
                short8 h0, h1, l0, l1;
                #pragma unroll
                for (int q = 0; q < 8; ++q) {
                    uint u = __float_as_uint(f[q]);
                    h0[q] = (short)(u >> 16);
                    float lo = f[q] - __uint_as_float(u & 0xffff0000u);
                    l0[q] = (short)(__float_as_uint(lo) >> 16);
                }
                #pragma unroll
                for (int q = 0; q < 8; ++q) {
                    uint u = __float_as_uint(f[8+q]);
                    h1[q] = (short)(u >> 16);
                    float lo = f[8+q] - __uint_as_float(u & 0xffff0000u);
                    l1[q] = (short)(__float_as_uint(lo) >> 16);
                }
                int g0 = sh * 2;
                *(short8*)(Ah + (g0 * 128 + sm) * 8)       = h0;
                *(short8*)(Ah + ((g0 + 1) * 128 + sm) * 8) = h1;
                *(short8*)(Al + (g0 * 128 + sm) * 8)       = l0;
                *(short8*)(Al + ((g0 + 1) * 128 + sm) * 8) = l1;
            }
            {
                float f[16];
                int gj = j0 + sm;
                if (gj < M) {
                    const float* p = B + (size_t)gj * K_DIM + k0;
                    #pragma unroll
                    for (int q = 0; q < 4; ++q) {
                        float4 x = *(const float4*)(p + q * 4);
                        f[q*4+0]=x.x; f[q*4+1]=x.y; f[q*4+2]=x.z; f[q*4+3]=x.w;
                    }
                } else {
                    #pragma unroll
                    for (int q = 0; q < 16; ++q) f[q] = 0.f;
                }
                short8 h0, h1, l0, l1;
                #pragma unroll
                for (int q = 0; q < 8; ++q) {
                    uint u = __float_as_uint(f[q]);
                    h0[q] = (short)(u >> 16);
                    float lo = f[q] - __uint_as_float(u & 0xffff0000u);
                    l0[q] = (short)(__float_as_uint(lo) >> 16);
                }
                #pragma unroll
                for (int q = 0; q < 8; ++q) {
                    uint u = __float_as_uint(f[8+q]);
                    h1[q] = (short)(u >> 16);
                    float lo = f[8+q] - __uint_as_float(u & 0xffff0000u);
                    l1[q] = (short)(__float_as_uint(lo) >> 16);
                }
                int g0 = sh * 2;
                *(short8*)(Bh + (g0 * 128 + sm) * 8)       = h0;
                *(short8*)(Bh + ((g0 + 1) * 128 + sm) * 8) = h1;
                *(short8*)(Bl + (g0 * 128 + sm) * 8)       = l0;
                *(short8*)(Bl + ((g0 + 1) * 128 + sm) * 8) = l1;
            }
            __syncthreads();

            bf16x8 a_h[4], a_l[4], b_h[4], b_l[4];
            #pragma unroll
            for (int fi = 0; fi < 4; ++fi) {
                int ra = (tg * 128 + wr + fi * 16 + tr) * 8;
                a_h[fi] = *(const bf16x8*)(Ah + ra);
                a_l[fi] = *(const bf16x8*)(Al + ra);
            }
            #pragma unroll
            for (int fj = 0; fj < 4; ++fj) {
                int rb = (tg * 128 + wc + fj * 16 + tr) * 8;
                b_h[fj] = *(const bf16x8*)(Bh + rb);
                b_l[fj] = *(const bf16x8*)(Bl + rb);
            }
            #pragma unroll
            for (int fi = 0; fi < 4; ++fi)
                #pragma unroll
                for (int fj = 0; fj < 4; ++fj) {
                    acc[fi][fj] = __builtin_amdgcn_mfma_f32_16x16x32_bf16(a_h[fi], b_h[fj], acc[fi][fj], 0, 0, 0);
                    acc[fi][fj] = __builtin_amdgcn_mfma_f32_16x16x32_bf16(a_h[fi], b_l[fj], acc[fi][fj], 0, 0, 0);
                    acc[fi][fj] = __builtin_amdgcn_mfma_f32_16x16x32_bf16(a_l[fi], b_h[fj], acc[fi][fj], 0, 0, 0);
                }
            __syncthreads();
        }

        #pragma unroll
        for (int fj = 0; fj < 4; ++fj) {
            int j = j0 + wc + fj * 16 + tr;
            float nbv = nb[j];
            #pragma unroll
            for (int fi = 0; fi < 4; ++fi)
                #pragma unroll
                for (int r = 0; r < 4; ++r) {
                    float s = fmaf(-2.f, acc[fi][fj][r], nbv);
                    localmin[fi * 4 + r] = fminf(localmin[fi * 4 + r], s);
                }
        }
    }

    #pragma unroll
    for (int u = 0; u < 16; ++u) {
        float v = localmin[u];
        #pragma unroll
        for (int m = 1; m < 16; m <<= 1) v = fminf(v, __shfl_xor(v, m, 64));
        localmin[u] = v;
    }
    if (tr == 0) {
        #pragma unroll
        for (int fi = 0; fi < 4; ++fi)
            #pragma unroll
            for (int r = 0; r < 4; ++r) {
                int i = i0 + wr + fi * 16 + tg * 4 + r;
                if (i < N) {
                    float v = fmaxf(na[i] + localmin[fi * 4 + r], 0.f);
                    atomicMin(&vmin[i], __float_as_uint(v));
                }
            }
    }
}

// ---------------------------------------------------------------------------
// Kernel 3: argmax over vmin (uint bits of non-negative floats).
// ---------------------------------------------------------------------------
__global__ __launch_bounds__(1024) void argmax_kernel(
    const unsigned* __restrict__ vmin, float* __restrict__ out, int N)
{
    unsigned long long best = 0ull;
    for (int i = threadIdx.x; i < N; i += 1024) {
        unsigned long long p =
            ((unsigned long long)vmin[i] << 32) | (unsigned)(~i);
        if (p > best) best = p;
    }
    #pragma unroll
    for (int m = 1; m < 64; m <<= 1) {
        unsigned hi = (unsigned)(best >> 32), lo = (unsigned)best;
        unsigned ohi = __shfl_xor(hi, m, 64);
        unsigned olo = __shfl_xor(lo, m, 64);
        unsigned long long o = ((unsigned long long)ohi << 32) | olo;
        if (o > best) best = o;
    }
    __shared__ unsigned long long sb[16];
    int lane = threadIdx.x & 63, w = threadIdx.x >> 6;
    if (lane == 0) sb[w] = best;
    __syncthreads();
    if (threadIdx.x == 0) {
        unsigned long long b = sb[0];
        #pragma unroll
        for (int w2 = 1; w2 < 16; ++w2) if (sb[w2] > b) b = sb[w2];
        unsigned idx = ~(unsigned)(b & 0xFFFFFFFFull);
        float v = __uint_as_float((unsigned)(b >> 32));
        out[0] = (float)idx;
        out[1] = sqrtf(v);
    }
}

// ---------------------------------------------------------------------------
extern "C" void kernel_launch(void* const* d_in, const int* in_sizes, int n_in,
                              void* d_out, int out_size, void* d_ws, size_t ws_size,
                              hipStream_t stream)
{
    const float* A = (const float*)d_in[0];
    const float* B = (const float*)d_in[1];
    const int N = in_sizes[0] / K_DIM;           // 50000
    const int M = in_sizes[1] / K_DIM;           // 5000
    const int ntile = (N + BM - 1) / BM;         // 391
    const int njt   = (M + BN - 1) / BN;         // 40
    const int Npad = ntile * BM, Mpad = njt * BN;

    char* ws = (char*)d_ws;
    float*    na   = (float*)ws;                     // Npad
    float*    nb   = na + Npad;                      // Mpad
    unsigned* vmin = (unsigned*)(nb + Mpad);         // Npad
    size_t off = ((size_t)(Npad + Mpad + Npad) * 4 + 255) & ~(size_t)255;
    size_t sizeA = (size_t)Npad * K_DIM;             // ushorts
    size_t sizeB = (size_t)Mpad * K_DIM;
    ushort* AhiW = (ushort*)(ws + off);
    ushort* AloW = AhiW + sizeA;
    ushort* BhiW = AloW + sizeA;
    ushort* BloW = BhiW + sizeB;
    size_t need = off + 2 * (sizeA + sizeB) * sizeof(ushort);

    float* out = (float*)d_out;

    int waves = Npad + Mpad;
    hipLaunchKernelGGL(norms_init_kernel, dim3((waves + 3) / 4), dim3(256), 0, stream,
                       A, B, na, nb, vmin, N, M, Npad, Mpad);

    if (ws_size >= need) {
        hipLaunchKernelGGL(preconvert_kernel, dim3((Npad * 64 + 255) / 256), dim3(256), 0, stream,
                           A, AhiW, AloW, N, Npad);
        hipLaunchKernelGGL(preconvert_kernel, dim3((Mpad * 64 + 255) / 256), dim3(256), 0, stream,
                           B, BhiW, BloW, M, Mpad);
        // grid: x = j-chunk (fast), y = A-tile (slow) -> chunks sharing a tile
        // are dispatch-adjacent
        hipLaunchKernelGGL(gemm_min_pre, dim3(JCHUNKS, ntile), dim3(256), 0, stream,
                           AhiW, AloW, BhiW, BloW, na, nb, vmin, N, njt);
    } else {
        hipLaunchKernelGGL(gemm_min_fused, dim3(JCHUNKS, ntile), dim3(256), 0, stream,
                           A, B, na, nb, vmin, N, M, njt);
    }

    hipLaunchKernelGGL(argmax_kernel, dim3(1), dim3(1024), 0, stream,
                       vmin, out, N);
}